// Round 11
// baseline (613.564 us; speedup 1.0000x reference)
//
#include <hip/hip_runtime.h>
#include <hip/hip_fp16.h>

// APPNP: K steps of D^{-1/2} A D^{-1/2} propagation + teleport, then MFMA MLP.
// R11: scatter writes 8B int2 entries (R10's 4B entries INCREASED line
// ping-pong: 16 random writers/64B line vs 8 -> 46->55us, WRITE_SIZE up).
// A streaming compact pass then extracts 4B src indices for prop so the
// 10 propagation steps keep cheap 4B/edge scalar reads.
// h_hat = norm (.) h folding retained: all edge weights are exactly 1.

#define N_NODES 100000
#define N_PAD   100032   // rows allocated (zero row at N_NODES + MLP slack)
#define N_EDGES 800000
#define D_DATA  100
#define H_DIM   256
#define N_CLS   47
#define K_STEPS 10
#define ALPHA   0.1f
#define HS      128      // fp16 row stride (halfs); cols 100..127 are zero
#define MB      64       // nodes per MLP block

#define SCAN_NB    200
#define SCAN_CHUNK 500   // 200*500 == N_NODES
#define EW_CAP (N_EDGES + 3 * N_NODES)

typedef _Float16 half8_t __attribute__((ext_vector_type(8)));
typedef float floatx4 __attribute__((ext_vector_type(4)));

// ---------------- CSR build ----------------

__global__ void deg_kernel(const int* __restrict__ dst, int* __restrict__ deg, int e) {
    int i = blockIdx.x * blockDim.x + threadIdx.x;
    if (i < e) atomicAdd(&deg[dst[i]], 1);
}

__global__ __launch_bounds__(256) void scan_partial_kernel(
        const int* __restrict__ deg, int* __restrict__ partials) {
    __shared__ int red[256];
    int t = threadIdx.x;
    int base = blockIdx.x * SCAN_CHUNK;
    int s = 0;
    int i0 = 2 * t, i1 = 2 * t + 1;
    if (i0 < SCAN_CHUNK) s += (deg[base + i0] + 3) & ~3;
    if (i1 < SCAN_CHUNK) s += (deg[base + i1] + 3) & ~3;
    red[t] = s;
    __syncthreads();
    for (int off = 128; off > 0; off >>= 1) {
        if (t < off) red[t] += red[t + off];
        __syncthreads();
    }
    if (t == 0) partials[blockIdx.x] = red[0];
}

__global__ __launch_bounds__(256) void scan_top_kernel(
        const int* __restrict__ partials, int* __restrict__ pofs,
        int* __restrict__ row_ptr) {
    __shared__ int s[256];
    int t = threadIdx.x;
    s[t] = (t < SCAN_NB) ? partials[t] : 0;
    __syncthreads();
    for (int off = 1; off < 256; off <<= 1) {
        int v = (t >= off) ? s[t - off] : 0;
        __syncthreads();
        s[t] += v;
        __syncthreads();
    }
    if (t < SCAN_NB) pofs[t] = s[t] - partials[t];
    if (t == SCAN_NB - 1) row_ptr[N_NODES] = s[t];   // padded total
}

__global__ __launch_bounds__(256) void scan_emit_kernel(
        const int* __restrict__ deg, const int* __restrict__ pofs,
        int* __restrict__ row_ptr, float* __restrict__ norm) {
    __shared__ int s[256];
    int t = threadIdx.x;
    int base = blockIdx.x * SCAN_CHUNK;
    int i0 = 2 * t, i1 = 2 * t + 1;
    int d0 = (i0 < SCAN_CHUNK) ? deg[base + i0] : 0;
    int d1 = (i1 < SCAN_CHUNK) ? deg[base + i1] : 0;
    int p0 = (d0 + 3) & ~3, p1 = (d1 + 3) & ~3;
    s[t] = p0 + p1;
    __syncthreads();
    for (int off = 1; off < 256; off <<= 1) {
        int v = (t >= off) ? s[t - off] : 0;
        __syncthreads();
        s[t] += v;
        __syncthreads();
    }
    int p = s[t] - (p0 + p1) + pofs[blockIdx.x];
    if (i0 < SCAN_CHUNK) {
        row_ptr[base + i0] = p;
        norm[base + i0] = rsqrtf((float)max(d0, 1));
    }
    if (i1 < SCAN_CHUNK) {
        row_ptr[base + i1] = p + p0;
        norm[base + i1] = rsqrtf((float)max(d1, 1));
    }
}

// scatter: 8B entries (src, 0) -> es8. 8 writers per 64B line (measured faster
// than 16-writers/line with 4B entries: cross-XCD line ping-pong dominates).
__global__ void scatter_kernel(const int* __restrict__ src, const int* __restrict__ dst,
                               const int* __restrict__ row_ptr, int* __restrict__ fill,
                               int2* __restrict__ es8, int e) {
    int i = blockIdx.x * blockDim.x + threadIdx.x;
    if (i < e) {
        int d = dst[i];
        int pos = row_ptr[d] + atomicAdd(&fill[d], 1);
        es8[pos] = make_int2(src[i], 0);
    }
}

// pad slots -> the zero row (index N_NODES); near-coalesced (consecutive
// threads write adjacent node ranges)
__global__ void pad_kernel(const int* __restrict__ deg, const int* __restrict__ row_ptr,
                           int2* __restrict__ es8, int n) {
    int i = blockIdx.x * blockDim.x + threadIdx.x;
    if (i < n) {
        int b = row_ptr[i] + deg[i];
        int e = row_ptr[i + 1];
        for (int s = b; s < e; ++s) es8[s] = make_int2(N_NODES, 0);
    }
}

// streaming compact: es4[i] = es8[i].x (prop reads 4B/edge; tail is unused)
__global__ void compact_kernel(const int2* __restrict__ es8, int* __restrict__ es4, int n) {
    int i = blockIdx.x * blockDim.x + threadIdx.x;
    if (i < n) es4[i] = es8[i].x;
}

// W1 [100][256] fp32 -> W1p: MFMA B-frags, 16 n-tiles x 4 k-steps, K padded 128.
__global__ void pack_w1_kernel(const float* __restrict__ W1, __half* __restrict__ W1p) {
    int idx = blockIdx.x * blockDim.x + threadIdx.x;   // 32768 halfs
    if (idx >= 16 * 4 * 64 * 8) return;
    int j = idx & 7;
    int lane = (idx >> 3) & 63;
    int ks = (idx >> 9) & 3;
    int nt = idx >> 11;
    int k = ks * 32 + (lane >> 4) * 8 + j;
    int n = nt * 16 + (lane & 15);
    float v = (k < D_DATA) ? W1[(size_t)k * H_DIM + n] : 0.f;
    W1p[idx] = __float2half(v);
}

// W2 [256][47] fp32 -> W2p: 3 n-tiles x 8 k-steps, N padded 48.
__global__ void pack_w2_kernel(const float* __restrict__ W2, __half* __restrict__ W2p) {
    int idx = blockIdx.x * blockDim.x + threadIdx.x;   // 12288 halfs
    if (idx >= 3 * 8 * 64 * 8) return;
    int j = idx & 7;
    int lane = (idx >> 3) & 63;
    int ks = (idx >> 9) & 7;
    int nt = idx >> 12;
    int k = ks * 32 + (lane >> 4) * 8 + j;
    int n = nt * 16 + (lane & 15);
    float v = (n < N_CLS) ? W2[(size_t)k * N_CLS + n] : 0.f;
    W2p[idx] = __float2half(v);
}

// x (fp32, dense) -> xhat16 = norm (.) x (fp16, stride 128, zero pads);
// row N_NODES is all zeros (gather target of CSR pad edges).
__global__ void convert_xhat_kernel(const float* __restrict__ x,
                                    const float* __restrict__ norm,
                                    __half2* __restrict__ xh, int n_half2) {
    int i = blockIdx.x * blockDim.x + threadIdx.x;
    if (i < n_half2) {
        int node = i >> 6;          // 64 half2 per row
        int c2 = i & 63;
        float2 v = make_float2(0.f, 0.f);
        if (node < N_NODES && c2 < D_DATA / 2) {
            float nn = norm[node];
            const float2* r = (const float2*)(x + (size_t)node * D_DATA);
            float2 xv = r[c2];
            v = make_float2(nn * xv.x, nn * xv.y);
        }
        xh[i] = __float22half2_rn(v);
    }
}

// zero row N_NODES of h16A and h16B
__global__ void zero_rows_kernel(__half2* __restrict__ a, __half2* __restrict__ b) {
    int i = threadIdx.x;   // 128 threads
    if (i < 64) a[(size_t)N_NODES * (HS / 2) + i] = __half2();
    else        b[(size_t)N_NODES * (HS / 2) + (i - 64)] = __half2();
}

// ---------------- propagation (h_hat space) ----------------
// One wave per node; lane l holds half2 l of the 256B row. Weightless gather:
// S[n] = sum of h_hat[src] rows; out = c*S + teleport. Padded CSR -> exact
// 8-wide then 4-wide batches.

__global__ __launch_bounds__(256) void prop_mid_kernel(
        const __half* __restrict__ hin, const __half* __restrict__ xhat,
        const float* __restrict__ norm, const int* __restrict__ row_ptr,
        const int* __restrict__ es, __half* __restrict__ hout, int n_nodes) {
    int lane = threadIdx.x & 63;
    int node = __builtin_amdgcn_readfirstlane(blockIdx.x * 4 + (threadIdx.x >> 6));
    if (node >= n_nodes) return;
    int beg = __builtin_amdgcn_readfirstlane(row_ptr[node]);
    int end = __builtin_amdgcn_readfirstlane(row_ptr[node + 1]);
    float nn = norm[node];                       // uniform -> s_load
    float c = (1.0f - ALPHA) * nn * nn;
    float ax = 0.f, ay = 0.f, bx = 0.f, by = 0.f;
    float cx = 0.f, cy = 0.f, dx = 0.f, dy = 0.f;
    int e = beg;
    for (; e + 8 <= end; e += 8) {
        int s[8];
#pragma unroll
        for (int j = 0; j < 8; ++j) s[j] = es[e + j];          // uniform -> s_load x8
        __half2 hv[8];
#pragma unroll
        for (int j = 0; j < 8; ++j)
            hv[j] = ((const __half2*)(hin + (size_t)s[j] * HS))[lane];
        float2 v[8];
#pragma unroll
        for (int j = 0; j < 8; ++j) v[j] = __half22float2(hv[j]);
        ax += v[0].x; ay += v[0].y;  bx += v[1].x; by += v[1].y;
        cx += v[2].x; cy += v[2].y;  dx += v[3].x; dy += v[3].y;
        ax += v[4].x; ay += v[4].y;  bx += v[5].x; by += v[5].y;
        cx += v[6].x; cy += v[6].y;  dx += v[7].x; dy += v[7].y;
    }
    if (e < end) {   // exactly one 4-batch (padded deg % 4 == 0)
        int s[4];
#pragma unroll
        for (int j = 0; j < 4; ++j) s[j] = es[e + j];
        __half2 hv[4];
#pragma unroll
        for (int j = 0; j < 4; ++j)
            hv[j] = ((const __half2*)(hin + (size_t)s[j] * HS))[lane];
#pragma unroll
        for (int j = 0; j < 4; ++j) {
            float2 v = __half22float2(hv[j]);
            ax += v.x; ay += v.y;
        }
    }
    float sx = (ax + bx) + (cx + dx);
    float sy = (ay + by) + (cy + dy);
    // teleport: alpha * xhat (branchless 64-lane fp16 read; pad cols zero)
    float2 t = __half22float2(((const __half2*)(xhat + (size_t)node * HS))[lane]);
    float2 o = make_float2(c * sx + ALPHA * t.x, c * sy + ALPHA * t.y);
    ((__half2*)(hout + (size_t)node * HS))[lane] = __float22half2_rn(o);
}

// final step: h = (1-alpha)*norm*S + alpha*x  (exact fp32 teleport)
__global__ __launch_bounds__(256) void prop_final_kernel(
        const __half* __restrict__ hin, const float* __restrict__ x,
        const float* __restrict__ norm, const int* __restrict__ row_ptr,
        const int* __restrict__ es, __half* __restrict__ hout, int n_nodes) {
    int lane = threadIdx.x & 63;
    int node = __builtin_amdgcn_readfirstlane(blockIdx.x * 4 + (threadIdx.x >> 6));
    if (node >= n_nodes) return;
    int beg = __builtin_amdgcn_readfirstlane(row_ptr[node]);
    int end = __builtin_amdgcn_readfirstlane(row_ptr[node + 1]);
    float nn = norm[node];
    float c = (1.0f - ALPHA) * nn;
    float ax = 0.f, ay = 0.f, bx = 0.f, by = 0.f;
    float cx = 0.f, cy = 0.f, dx = 0.f, dy = 0.f;
    int e = beg;
    for (; e + 8 <= end; e += 8) {
        int s[8];
#pragma unroll
        for (int j = 0; j < 8; ++j) s[j] = es[e + j];
        __half2 hv[8];
#pragma unroll
        for (int j = 0; j < 8; ++j)
            hv[j] = ((const __half2*)(hin + (size_t)s[j] * HS))[lane];
        float2 v[8];
#pragma unroll
        for (int j = 0; j < 8; ++j) v[j] = __half22float2(hv[j]);
        ax += v[0].x; ay += v[0].y;  bx += v[1].x; by += v[1].y;
        cx += v[2].x; cy += v[2].y;  dx += v[3].x; dy += v[3].y;
        ax += v[4].x; ay += v[4].y;  bx += v[5].x; by += v[5].y;
        cx += v[6].x; cy += v[6].y;  dx += v[7].x; dy += v[7].y;
    }
    if (e < end) {
        int s[4];
#pragma unroll
        for (int j = 0; j < 4; ++j) s[j] = es[e + j];
        __half2 hv[4];
#pragma unroll
        for (int j = 0; j < 4; ++j)
            hv[j] = ((const __half2*)(hin + (size_t)s[j] * HS))[lane];
#pragma unroll
        for (int j = 0; j < 4; ++j) {
            float2 v = __half22float2(hv[j]);
            ax += v.x; ay += v.y;
        }
    }
    float sx = (ax + bx) + (cx + dx);
    float sy = (ay + by) + (cy + dy);
    float2 xv = make_float2(0.f, 0.f);
    if (lane < D_DATA / 2)
        xv = ((const float2*)(x + (size_t)node * D_DATA))[lane];
    float2 o = make_float2(c * sx + ALPHA * xv.x, c * sy + ALPHA * xv.y);
    ((__half2*)(hout + (size_t)node * HS))[lane] = __float22half2_rn(o);
}

// ---------------- MFMA MLP (unchanged from R9/R10) ----------------

#define ZP 264

__global__ __launch_bounds__(256, 4) void mlp_mfma_kernel(
        const __half* __restrict__ h16,
        const __half* __restrict__ W1p, const float* __restrict__ b1,
        const __half* __restrict__ W2p, const float* __restrict__ b2,
        float* __restrict__ out, int n_nodes) {
    __shared__ _Float16 zs[MB][ZP];   // 33 KB -> 4 blocks/CU
    int tid = threadIdx.x;
    int lane = tid & 63;
    int w = tid >> 6;
    int q = lane >> 4;
    int r = lane & 15;
    int node0 = blockIdx.x * MB + w * 16;

    half8_t a1[4];
#pragma unroll
    for (int ks = 0; ks < 4; ++ks)
        a1[ks] = *(const half8_t*)(h16 + (size_t)(node0 + r) * HS + ks * 32 + q * 8);

    const half8_t* w1f = (const half8_t*)W1p;
#pragma unroll 4
    for (int nt = 0; nt < 16; ++nt) {
        floatx4 acc = {0.f, 0.f, 0.f, 0.f};
#pragma unroll
        for (int ks = 0; ks < 4; ++ks) {
            half8_t b = w1f[(nt * 4 + ks) * 64 + lane];
            acc = __builtin_amdgcn_mfma_f32_16x16x32_f16(a1[ks], b, acc, 0, 0, 0);
        }
        float bb = b1[nt * 16 + r];
#pragma unroll
        for (int reg = 0; reg < 4; ++reg) {
            float zv = fmaxf(acc[reg] + bb, 0.f);
            zs[w * 16 + q * 4 + reg][nt * 16 + r] = (_Float16)zv;
        }
    }

    half8_t a2[8];
#pragma unroll
    for (int ks = 0; ks < 8; ++ks)
        a2[ks] = *(const half8_t*)&zs[w * 16 + r][ks * 32 + q * 8];

    const half8_t* w2f = (const half8_t*)W2p;
#pragma unroll
    for (int nt = 0; nt < 3; ++nt) {
        floatx4 acc = {0.f, 0.f, 0.f, 0.f};
#pragma unroll
        for (int ks = 0; ks < 8; ++ks) {
            half8_t b = w2f[(nt * 8 + ks) * 64 + lane];
            acc = __builtin_amdgcn_mfma_f32_16x16x32_f16(a2[ks], b, acc, 0, 0, 0);
        }
        int c = nt * 16 + r;
        if (c < N_CLS) {
            float bb = b2[c];
#pragma unroll
            for (int reg = 0; reg < 4; ++reg) {
                int node = node0 + q * 4 + reg;
                if (node < n_nodes)
                    out[(size_t)node * N_CLS + c] = acc[reg] + bb;
            }
        }
    }
}

// ---------------- launch ----------------

static inline size_t align_up(size_t v, size_t a) { return (v + a - 1) & ~(a - 1); }

extern "C" void kernel_launch(void* const* d_in, const int* in_sizes, int n_in,
                              void* d_out, int out_size, void* d_ws, size_t ws_size,
                              hipStream_t stream) {
    const float* x   = (const float*)d_in[0];
    const int*   src = (const int*)d_in[1];
    const int*   dst = (const int*)d_in[2];
    const float* W1  = (const float*)d_in[3];
    const float* b1  = (const float*)d_in[4];
    const float* W2  = (const float*)d_in[5];
    const float* b2  = (const float*)d_in[6];
    float* out = (float*)d_out;

    char* p = (char*)d_ws;
    size_t off = 0;
    int* deg = (int*)(p + off);           off = align_up(off + N_NODES * 4, 256);
    int* row_ptr = (int*)(p + off);       off = align_up(off + (N_NODES + 1) * 4, 256);
    int* fill = (int*)(p + off);          off = align_up(off + N_NODES * 4, 256);
    float* norm = (float*)(p + off);      off = align_up(off + N_NODES * 4, 256);
    int* partials = (int*)(p + off);      off = align_up(off + SCAN_NB * 4, 256);
    int* pofs = (int*)(p + off);          off = align_up(off + SCAN_NB * 4, 256);
    __half* W1p = (__half*)(p + off);     off = align_up(off + 16 * 4 * 64 * 8 * 2, 256);
    __half* W2p = (__half*)(p + off);     off = align_up(off + 3 * 8 * 64 * 8 * 2, 256);
    int2* es8 = (int2*)(p + off);         off = align_up(off + (size_t)EW_CAP * 8, 256);
    int* es4 = (int*)(p + off);           off = align_up(off + (size_t)EW_CAP * 4, 256);
    __half* xhat = (__half*)(p + off);    off = align_up(off + (size_t)N_PAD * HS * 2, 256);
    __half* h16A = (__half*)(p + off);    off = align_up(off + (size_t)N_PAD * HS * 2, 256);
    __half* h16B = (__half*)(p + off);    off = align_up(off + (size_t)N_PAD * HS * 2, 256);
    (void)ws_size;

    hipMemsetAsync(deg, 0, N_NODES * 4, stream);
    hipMemsetAsync(fill, 0, N_NODES * 4, stream);

    int eb = (N_EDGES + 255) / 256;
    deg_kernel<<<eb, 256, 0, stream>>>(dst, deg, N_EDGES);
    scan_partial_kernel<<<SCAN_NB, 256, 0, stream>>>(deg, partials);
    scan_top_kernel<<<1, 256, 0, stream>>>(partials, pofs, row_ptr);
    scan_emit_kernel<<<SCAN_NB, 256, 0, stream>>>(deg, pofs, row_ptr, norm);
    scatter_kernel<<<eb, 256, 0, stream>>>(src, dst, row_ptr, fill, es8, N_EDGES);
    pad_kernel<<<(N_NODES + 255) / 256, 256, 0, stream>>>(deg, row_ptr, es8, N_NODES);
    compact_kernel<<<(EW_CAP + 255) / 256, 256, 0, stream>>>(es8, es4, EW_CAP);
    pack_w1_kernel<<<128, 256, 0, stream>>>(W1, W1p);
    pack_w2_kernel<<<48, 256, 0, stream>>>(W2, W2p);

    int nh2 = (N_NODES + 1) * (HS / 2);   // includes the zero row
    convert_xhat_kernel<<<(nh2 + 255) / 256, 256, 0, stream>>>(x, norm, (__half2*)xhat, nh2);
    zero_rows_kernel<<<1, 128, 0, stream>>>((__half2*)h16A, (__half2*)h16B);

    int pb = N_NODES / 4;   // 4 waves (nodes) per block
    // k=0: xhat -> A; k=1..8 ping-pong (odd->B, even->A); k=9 final: A -> B
    prop_mid_kernel<<<pb, 256, 0, stream>>>(xhat, xhat, norm, row_ptr, es4, h16A, N_NODES);
    const __half* hin = h16A;
    for (int k = 1; k < K_STEPS - 1; ++k) {
        __half* ho = (k & 1) ? h16B : h16A;
        prop_mid_kernel<<<pb, 256, 0, stream>>>(hin, xhat, norm, row_ptr, es4, ho, N_NODES);
        hin = ho;
    }
    prop_final_kernel<<<pb, 256, 0, stream>>>(hin, x, norm, row_ptr, es4, h16B, N_NODES);

    int mb = (N_NODES + MB - 1) / MB;
    mlp_mfma_kernel<<<mb, 256, 0, stream>>>(h16B, W1p, b1, W2p, b2, out, N_NODES);
}

// Round 12
// 552.815 us; speedup vs baseline: 1.1099x; 1.1099x over previous
//
#include <hip/hip_runtime.h>
#include <hip/hip_fp16.h>

// APPNP: K steps of D^{-1/2} A D^{-1/2} propagation + teleport, then MFMA MLP.
// R12: (a) deg pass records each edge's slot (atomicAdd return) -> scatter is
// ATOMIC-FREE (one random 4B store; R11 proved entry size is irrelevant);
// fill/memset/compact dropped. (b) prop pairs 2 nodes per wave (two indep
// accumulator sets, 8 gathers in flight) to halve per-wave startup chains
// without R8's in-flight reduction.
// h_hat = norm (.) h folding retained: all edge weights are exactly 1.

#define N_NODES 100000
#define N_PAD   100032   // rows allocated (zero row at N_NODES + MLP slack)
#define N_EDGES 800000
#define D_DATA  100
#define H_DIM   256
#define N_CLS   47
#define K_STEPS 10
#define ALPHA   0.1f
#define HS      128      // fp16 row stride (halfs); cols 100..127 are zero
#define MB      64       // nodes per MLP block

#define SCAN_NB    200
#define SCAN_CHUNK 500   // 200*500 == N_NODES
#define EW_CAP (N_EDGES + 3 * N_NODES)

typedef _Float16 half8_t __attribute__((ext_vector_type(8)));
typedef float floatx4 __attribute__((ext_vector_type(4)));

// ---------------- CSR build ----------------

// histogram + per-edge slot (within-dst rank; order irrelevant, weights are 1)
__global__ void deg_kernel(const int* __restrict__ dst, int* __restrict__ deg,
                           int* __restrict__ slot, int e) {
    int i = blockIdx.x * blockDim.x + threadIdx.x;
    if (i < e) slot[i] = atomicAdd(&deg[dst[i]], 1);
}

__global__ __launch_bounds__(256) void scan_partial_kernel(
        const int* __restrict__ deg, int* __restrict__ partials) {
    __shared__ int red[256];
    int t = threadIdx.x;
    int base = blockIdx.x * SCAN_CHUNK;
    int s = 0;
    int i0 = 2 * t, i1 = 2 * t + 1;
    if (i0 < SCAN_CHUNK) s += (deg[base + i0] + 3) & ~3;
    if (i1 < SCAN_CHUNK) s += (deg[base + i1] + 3) & ~3;
    red[t] = s;
    __syncthreads();
    for (int off = 128; off > 0; off >>= 1) {
        if (t < off) red[t] += red[t + off];
        __syncthreads();
    }
    if (t == 0) partials[blockIdx.x] = red[0];
}

__global__ __launch_bounds__(256) void scan_top_kernel(
        const int* __restrict__ partials, int* __restrict__ pofs,
        int* __restrict__ row_ptr) {
    __shared__ int s[256];
    int t = threadIdx.x;
    s[t] = (t < SCAN_NB) ? partials[t] : 0;
    __syncthreads();
    for (int off = 1; off < 256; off <<= 1) {
        int v = (t >= off) ? s[t - off] : 0;
        __syncthreads();
        s[t] += v;
        __syncthreads();
    }
    if (t < SCAN_NB) pofs[t] = s[t] - partials[t];
    if (t == SCAN_NB - 1) row_ptr[N_NODES] = s[t];   // padded total
}

__global__ __launch_bounds__(256) void scan_emit_kernel(
        const int* __restrict__ deg, const int* __restrict__ pofs,
        int* __restrict__ row_ptr, float* __restrict__ norm) {
    __shared__ int s[256];
    int t = threadIdx.x;
    int base = blockIdx.x * SCAN_CHUNK;
    int i0 = 2 * t, i1 = 2 * t + 1;
    int d0 = (i0 < SCAN_CHUNK) ? deg[base + i0] : 0;
    int d1 = (i1 < SCAN_CHUNK) ? deg[base + i1] : 0;
    int p0 = (d0 + 3) & ~3, p1 = (d1 + 3) & ~3;
    s[t] = p0 + p1;
    __syncthreads();
    for (int off = 1; off < 256; off <<= 1) {
        int v = (t >= off) ? s[t - off] : 0;
        __syncthreads();
        s[t] += v;
        __syncthreads();
    }
    int p = s[t] - (p0 + p1) + pofs[blockIdx.x];
    if (i0 < SCAN_CHUNK) {
        row_ptr[base + i0] = p;
        norm[base + i0] = rsqrtf((float)max(d0, 1));
    }
    if (i1 < SCAN_CHUNK) {
        row_ptr[base + i1] = p + p0;
        norm[base + i1] = rsqrtf((float)max(d1, 1));
    }
}

// atomic-free scatter: position was fixed by the deg pass
__global__ void scatter_kernel(const int* __restrict__ src, const int* __restrict__ dst,
                               const int* __restrict__ slot,
                               const int* __restrict__ row_ptr,
                               int* __restrict__ es, int e) {
    int i = blockIdx.x * blockDim.x + threadIdx.x;
    if (i < e) es[row_ptr[dst[i]] + slot[i]] = src[i];
}

// pad slots -> the zero row (index N_NODES)
__global__ void pad_kernel(const int* __restrict__ deg, const int* __restrict__ row_ptr,
                           int* __restrict__ es, int n) {
    int i = blockIdx.x * blockDim.x + threadIdx.x;
    if (i < n) {
        int b = row_ptr[i] + deg[i];
        int e = row_ptr[i + 1];
        for (int s = b; s < e; ++s) es[s] = N_NODES;
    }
}

// W1 [100][256] fp32 -> W1p: MFMA B-frags, 16 n-tiles x 4 k-steps, K padded 128.
__global__ void pack_w1_kernel(const float* __restrict__ W1, __half* __restrict__ W1p) {
    int idx = blockIdx.x * blockDim.x + threadIdx.x;   // 32768 halfs
    if (idx >= 16 * 4 * 64 * 8) return;
    int j = idx & 7;
    int lane = (idx >> 3) & 63;
    int ks = (idx >> 9) & 3;
    int nt = idx >> 11;
    int k = ks * 32 + (lane >> 4) * 8 + j;
    int n = nt * 16 + (lane & 15);
    float v = (k < D_DATA) ? W1[(size_t)k * H_DIM + n] : 0.f;
    W1p[idx] = __float2half(v);
}

// W2 [256][47] fp32 -> W2p: 3 n-tiles x 8 k-steps, N padded 48.
__global__ void pack_w2_kernel(const float* __restrict__ W2, __half* __restrict__ W2p) {
    int idx = blockIdx.x * blockDim.x + threadIdx.x;   // 12288 halfs
    if (idx >= 3 * 8 * 64 * 8) return;
    int j = idx & 7;
    int lane = (idx >> 3) & 63;
    int ks = (idx >> 9) & 7;
    int nt = idx >> 12;
    int k = ks * 32 + (lane >> 4) * 8 + j;
    int n = nt * 16 + (lane & 15);
    float v = (n < N_CLS) ? W2[(size_t)k * N_CLS + n] : 0.f;
    W2p[idx] = __float2half(v);
}

// x (fp32, dense) -> xhat16 = norm (.) x (fp16, stride 128, zero pads);
// row N_NODES is all zeros (gather target of CSR pad edges).
__global__ void convert_xhat_kernel(const float* __restrict__ x,
                                    const float* __restrict__ norm,
                                    __half2* __restrict__ xh, int n_half2) {
    int i = blockIdx.x * blockDim.x + threadIdx.x;
    if (i < n_half2) {
        int node = i >> 6;          // 64 half2 per row
        int c2 = i & 63;
        float2 v = make_float2(0.f, 0.f);
        if (node < N_NODES && c2 < D_DATA / 2) {
            float nn = norm[node];
            const float2* r = (const float2*)(x + (size_t)node * D_DATA);
            float2 xv = r[c2];
            v = make_float2(nn * xv.x, nn * xv.y);
        }
        xh[i] = __float22half2_rn(v);
    }
}

// zero row N_NODES of h16A and h16B
__global__ void zero_rows_kernel(__half2* __restrict__ a, __half2* __restrict__ b) {
    int i = threadIdx.x;   // 128 threads
    if (i < 64) a[(size_t)N_NODES * (HS / 2) + i] = __half2();
    else        b[(size_t)N_NODES * (HS / 2) + (i - 64)] = __half2();
}

// ---------------- propagation (h_hat space, 2 nodes per wave) ----------------
// Lane l holds half2 l of each 256B row. Per iteration the wave issues node
// A's and node B's 4-edge batches together (8 gathers in flight); separate
// accumulators. All control is wave-uniform (bounds via readfirstlane).

__global__ __launch_bounds__(256) void prop_mid_kernel(
        const __half* __restrict__ hin, const __half* __restrict__ xhat,
        const float* __restrict__ norm, const int* __restrict__ row_ptr,
        const int* __restrict__ es, __half* __restrict__ hout, int n_nodes) {
    int lane = threadIdx.x & 63;
    int wave = blockIdx.x * 4 + (threadIdx.x >> 6);
    int nA = __builtin_amdgcn_readfirstlane(wave * 2);
    if (nA >= n_nodes) return;
    int nB = nA + 1;
    int begA = __builtin_amdgcn_readfirstlane(row_ptr[nA]);
    int begB = __builtin_amdgcn_readfirstlane(row_ptr[nB]);
    int endB = __builtin_amdgcn_readfirstlane(row_ptr[nB + 1]);
    int nbA = (begB - begA) >> 2;   // 4-edge batches (padded deg % 4 == 0)
    int nbB = (endB - begB) >> 2;
    int mb = nbA > nbB ? nbA : nbB;

    float a0x = 0.f, a0y = 0.f, a1x = 0.f, a1y = 0.f;   // node A, 2 chains
    float b0x = 0.f, b0y = 0.f, b1x = 0.f, b1y = 0.f;   // node B, 2 chains
    for (int it = 0; it < mb; ++it) {
        bool doA = it < nbA, doB = it < nbB;   // uniform
        int sA[4], sB[4];
        if (doA) {
            int e = begA + it * 4;
#pragma unroll
            for (int j = 0; j < 4; ++j) sA[j] = es[e + j];   // uniform -> s_load
        }
        if (doB) {
            int e = begB + it * 4;
#pragma unroll
            for (int j = 0; j < 4; ++j) sB[j] = es[e + j];
        }
        __half2 hvA[4], hvB[4];
        if (doA) {
#pragma unroll
            for (int j = 0; j < 4; ++j)
                hvA[j] = ((const __half2*)(hin + (size_t)sA[j] * HS))[lane];
        }
        if (doB) {
#pragma unroll
            for (int j = 0; j < 4; ++j)
                hvB[j] = ((const __half2*)(hin + (size_t)sB[j] * HS))[lane];
        }
        if (doA) {
            float2 v0 = __half22float2(hvA[0]), v1 = __half22float2(hvA[1]);
            float2 v2 = __half22float2(hvA[2]), v3 = __half22float2(hvA[3]);
            a0x += v0.x + v2.x; a0y += v0.y + v2.y;
            a1x += v1.x + v3.x; a1y += v1.y + v3.y;
        }
        if (doB) {
            float2 v0 = __half22float2(hvB[0]), v1 = __half22float2(hvB[1]);
            float2 v2 = __half22float2(hvB[2]), v3 = __half22float2(hvB[3]);
            b0x += v0.x + v2.x; b0y += v0.y + v2.y;
            b1x += v1.x + v3.x; b1y += v1.y + v3.y;
        }
    }
    {   // node A epilogue
        float nn = norm[nA];
        float c = (1.0f - ALPHA) * nn * nn;
        float2 t = __half22float2(((const __half2*)(xhat + (size_t)nA * HS))[lane]);
        float2 o = make_float2(c * (a0x + a1x) + ALPHA * t.x,
                               c * (a0y + a1y) + ALPHA * t.y);
        ((__half2*)(hout + (size_t)nA * HS))[lane] = __float22half2_rn(o);
    }
    {   // node B epilogue
        float nn = norm[nB];
        float c = (1.0f - ALPHA) * nn * nn;
        float2 t = __half22float2(((const __half2*)(xhat + (size_t)nB * HS))[lane]);
        float2 o = make_float2(c * (b0x + b1x) + ALPHA * t.x,
                               c * (b0y + b1y) + ALPHA * t.y);
        ((__half2*)(hout + (size_t)nB * HS))[lane] = __float22half2_rn(o);
    }
}

// final step: h = (1-alpha)*norm*S + alpha*x (exact fp32 teleport), fp16 out
__global__ __launch_bounds__(256) void prop_final_kernel(
        const __half* __restrict__ hin, const float* __restrict__ x,
        const float* __restrict__ norm, const int* __restrict__ row_ptr,
        const int* __restrict__ es, __half* __restrict__ hout, int n_nodes) {
    int lane = threadIdx.x & 63;
    int wave = blockIdx.x * 4 + (threadIdx.x >> 6);
    int nA = __builtin_amdgcn_readfirstlane(wave * 2);
    if (nA >= n_nodes) return;
    int nB = nA + 1;
    int begA = __builtin_amdgcn_readfirstlane(row_ptr[nA]);
    int begB = __builtin_amdgcn_readfirstlane(row_ptr[nB]);
    int endB = __builtin_amdgcn_readfirstlane(row_ptr[nB + 1]);
    int nbA = (begB - begA) >> 2;
    int nbB = (endB - begB) >> 2;
    int mb = nbA > nbB ? nbA : nbB;

    float a0x = 0.f, a0y = 0.f, a1x = 0.f, a1y = 0.f;
    float b0x = 0.f, b0y = 0.f, b1x = 0.f, b1y = 0.f;
    for (int it = 0; it < mb; ++it) {
        bool doA = it < nbA, doB = it < nbB;
        int sA[4], sB[4];
        if (doA) {
            int e = begA + it * 4;
#pragma unroll
            for (int j = 0; j < 4; ++j) sA[j] = es[e + j];
        }
        if (doB) {
            int e = begB + it * 4;
#pragma unroll
            for (int j = 0; j < 4; ++j) sB[j] = es[e + j];
        }
        __half2 hvA[4], hvB[4];
        if (doA) {
#pragma unroll
            for (int j = 0; j < 4; ++j)
                hvA[j] = ((const __half2*)(hin + (size_t)sA[j] * HS))[lane];
        }
        if (doB) {
#pragma unroll
            for (int j = 0; j < 4; ++j)
                hvB[j] = ((const __half2*)(hin + (size_t)sB[j] * HS))[lane];
        }
        if (doA) {
            float2 v0 = __half22float2(hvA[0]), v1 = __half22float2(hvA[1]);
            float2 v2 = __half22float2(hvA[2]), v3 = __half22float2(hvA[3]);
            a0x += v0.x + v2.x; a0y += v0.y + v2.y;
            a1x += v1.x + v3.x; a1y += v1.y + v3.y;
        }
        if (doB) {
            float2 v0 = __half22float2(hvB[0]), v1 = __half22float2(hvB[1]);
            float2 v2 = __half22float2(hvB[2]), v3 = __half22float2(hvB[3]);
            b0x += v0.x + v2.x; b0y += v0.y + v2.y;
            b1x += v1.x + v3.x; b1y += v1.y + v3.y;
        }
    }
    {
        float c = (1.0f - ALPHA) * norm[nA];
        float2 xv = make_float2(0.f, 0.f);
        if (lane < D_DATA / 2)
            xv = ((const float2*)(x + (size_t)nA * D_DATA))[lane];
        float2 o = make_float2(c * (a0x + a1x) + ALPHA * xv.x,
                               c * (a0y + a1y) + ALPHA * xv.y);
        ((__half2*)(hout + (size_t)nA * HS))[lane] = __float22half2_rn(o);
    }
    {
        float c = (1.0f - ALPHA) * norm[nB];
        float2 xv = make_float2(0.f, 0.f);
        if (lane < D_DATA / 2)
            xv = ((const float2*)(x + (size_t)nB * D_DATA))[lane];
        float2 o = make_float2(c * (b0x + b1x) + ALPHA * xv.x,
                               c * (b0y + b1y) + ALPHA * xv.y);
        ((__half2*)(hout + (size_t)nB * HS))[lane] = __float22half2_rn(o);
    }
}

// ---------------- MFMA MLP (unchanged from R9-R11) ----------------

#define ZP 264

__global__ __launch_bounds__(256, 4) void mlp_mfma_kernel(
        const __half* __restrict__ h16,
        const __half* __restrict__ W1p, const float* __restrict__ b1,
        const __half* __restrict__ W2p, const float* __restrict__ b2,
        float* __restrict__ out, int n_nodes) {
    __shared__ _Float16 zs[MB][ZP];   // 33 KB -> 4 blocks/CU
    int tid = threadIdx.x;
    int lane = tid & 63;
    int w = tid >> 6;
    int q = lane >> 4;
    int r = lane & 15;
    int node0 = blockIdx.x * MB + w * 16;

    half8_t a1[4];
#pragma unroll
    for (int ks = 0; ks < 4; ++ks)
        a1[ks] = *(const half8_t*)(h16 + (size_t)(node0 + r) * HS + ks * 32 + q * 8);

    const half8_t* w1f = (const half8_t*)W1p;
#pragma unroll 4
    for (int nt = 0; nt < 16; ++nt) {
        floatx4 acc = {0.f, 0.f, 0.f, 0.f};
#pragma unroll
        for (int ks = 0; ks < 4; ++ks) {
            half8_t b = w1f[(nt * 4 + ks) * 64 + lane];
            acc = __builtin_amdgcn_mfma_f32_16x16x32_f16(a1[ks], b, acc, 0, 0, 0);
        }
        float bb = b1[nt * 16 + r];
#pragma unroll
        for (int reg = 0; reg < 4; ++reg) {
            float zv = fmaxf(acc[reg] + bb, 0.f);
            zs[w * 16 + q * 4 + reg][nt * 16 + r] = (_Float16)zv;
        }
    }

    half8_t a2[8];
#pragma unroll
    for (int ks = 0; ks < 8; ++ks)
        a2[ks] = *(const half8_t*)&zs[w * 16 + r][ks * 32 + q * 8];

    const half8_t* w2f = (const half8_t*)W2p;
#pragma unroll
    for (int nt = 0; nt < 3; ++nt) {
        floatx4 acc = {0.f, 0.f, 0.f, 0.f};
#pragma unroll
        for (int ks = 0; ks < 8; ++ks) {
            half8_t b = w2f[(nt * 8 + ks) * 64 + lane];
            acc = __builtin_amdgcn_mfma_f32_16x16x32_f16(a2[ks], b, acc, 0, 0, 0);
        }
        int c = nt * 16 + r;
        if (c < N_CLS) {
            float bb = b2[c];
#pragma unroll
            for (int reg = 0; reg < 4; ++reg) {
                int node = node0 + q * 4 + reg;
                if (node < n_nodes)
                    out[(size_t)node * N_CLS + c] = acc[reg] + bb;
            }
        }
    }
}

// ---------------- launch ----------------

static inline size_t align_up(size_t v, size_t a) { return (v + a - 1) & ~(a - 1); }

extern "C" void kernel_launch(void* const* d_in, const int* in_sizes, int n_in,
                              void* d_out, int out_size, void* d_ws, size_t ws_size,
                              hipStream_t stream) {
    const float* x   = (const float*)d_in[0];
    const int*   src = (const int*)d_in[1];
    const int*   dst = (const int*)d_in[2];
    const float* W1  = (const float*)d_in[3];
    const float* b1  = (const float*)d_in[4];
    const float* W2  = (const float*)d_in[5];
    const float* b2  = (const float*)d_in[6];
    float* out = (float*)d_out;

    char* p = (char*)d_ws;
    size_t off = 0;
    int* deg = (int*)(p + off);           off = align_up(off + N_NODES * 4, 256);
    int* row_ptr = (int*)(p + off);       off = align_up(off + (N_NODES + 1) * 4, 256);
    int* slot = (int*)(p + off);          off = align_up(off + (size_t)N_EDGES * 4, 256);
    float* norm = (float*)(p + off);      off = align_up(off + N_NODES * 4, 256);
    int* partials = (int*)(p + off);      off = align_up(off + SCAN_NB * 4, 256);
    int* pofs = (int*)(p + off);          off = align_up(off + SCAN_NB * 4, 256);
    __half* W1p = (__half*)(p + off);     off = align_up(off + 16 * 4 * 64 * 8 * 2, 256);
    __half* W2p = (__half*)(p + off);     off = align_up(off + 3 * 8 * 64 * 8 * 2, 256);
    int* es = (int*)(p + off);            off = align_up(off + (size_t)EW_CAP * 4, 256);
    __half* xhat = (__half*)(p + off);    off = align_up(off + (size_t)N_PAD * HS * 2, 256);
    __half* h16A = (__half*)(p + off);    off = align_up(off + (size_t)N_PAD * HS * 2, 256);
    __half* h16B = (__half*)(p + off);    off = align_up(off + (size_t)N_PAD * HS * 2, 256);
    (void)ws_size;

    hipMemsetAsync(deg, 0, N_NODES * 4, stream);

    int eb = (N_EDGES + 255) / 256;
    deg_kernel<<<eb, 256, 0, stream>>>(dst, deg, slot, N_EDGES);
    scan_partial_kernel<<<SCAN_NB, 256, 0, stream>>>(deg, partials);
    scan_top_kernel<<<1, 256, 0, stream>>>(partials, pofs, row_ptr);
    scan_emit_kernel<<<SCAN_NB, 256, 0, stream>>>(deg, pofs, row_ptr, norm);
    scatter_kernel<<<eb, 256, 0, stream>>>(src, dst, slot, row_ptr, es, N_EDGES);
    pad_kernel<<<(N_NODES + 255) / 256, 256, 0, stream>>>(deg, row_ptr, es, N_NODES);
    pack_w1_kernel<<<128, 256, 0, stream>>>(W1, W1p);
    pack_w2_kernel<<<48, 256, 0, stream>>>(W2, W2p);

    int nh2 = (N_NODES + 1) * (HS / 2);   // includes the zero row
    convert_xhat_kernel<<<(nh2 + 255) / 256, 256, 0, stream>>>(x, norm, (__half2*)xhat, nh2);
    zero_rows_kernel<<<1, 128, 0, stream>>>((__half2*)h16A, (__half2*)h16B);

    int pb = (N_NODES / 2) / 4;   // 50000 node-pairs, 4 waves per block
    // k=0: xhat -> A; k=1..8 ping-pong (odd->B, even->A); k=9 final: A -> B
    prop_mid_kernel<<<pb, 256, 0, stream>>>(xhat, xhat, norm, row_ptr, es, h16A, N_NODES);
    const __half* hin = h16A;
    for (int k = 1; k < K_STEPS - 1; ++k) {
        __half* ho = (k & 1) ? h16B : h16A;
        prop_mid_kernel<<<pb, 256, 0, stream>>>(hin, xhat, norm, row_ptr, es, ho, N_NODES);
        hin = ho;
    }
    prop_final_kernel<<<pb, 256, 0, stream>>>(hin, x, norm, row_ptr, es, h16B, N_NODES);

    int mb = (N_NODES + MB - 1) / MB;
    mlp_mfma_kernel<<<mb, 256, 0, stream>>>(h16B, W1p, b1, W2p, b2, out, N_NODES);
}